// Round 1
// baseline (99.597 us; speedup 1.0000x reference)
//
#include <hip/hip_runtime.h>
#include <hip/hip_bf16.h>

#define DIM 1024
#define T_LEN 2048
#define NB 2
#define NH 16
#define HD 64
#define QBLK 64
#define KBLK 64
#define NQT (T_LEN / QBLK)   // 32

typedef float f32x4 __attribute__((ext_vector_type(4)));
typedef __bf16 bf16x8 __attribute__((ext_vector_type(8)));

__device__ __forceinline__ float sgnf(float v) {
    return (v > 0.f) ? 1.f : ((v < 0.f) ? -1.f : 0.f);
}

__global__ __launch_bounds__(256) void mba_kernel(
    const float* __restrict__ x,
    const float* __restrict__ bvq,
    const float* __restrict__ bvk,
    const float* __restrict__ bvv,
    float* __restrict__ out)
{
    // LDS: K tile row-major (gated by sgn(bv_k)), V tile transposed (gated by
    // sgn(bv_v)), P scratch per wave. Stride 72 bf16 (144 B) breaks the
    // 128B-row same-bank alignment and keeps 16B alignment for b128 ops.
    __shared__ __align__(16) __bf16 Kb[KBLK][72];
    __shared__ __align__(16) __bf16 Vt[HD][72];
    __shared__ __align__(16) __bf16 Pb[4][16][72];

    const int bid = blockIdx.x;
    const int qt  = (NQT - 1) - (bid & (NQT - 1));   // heavy tiles first
    const int bh  = bid >> 5;                        // 0..31
    const int b   = bh >> 4;
    const int h   = bh & 15;

    const int tid = threadIdx.x;
    const int w   = tid >> 6;     // wave 0..3
    const int l   = tid & 63;
    const int lq  = l & 15;       // lane-in-16
    const int lh  = l >> 4;       // quarter 0..3

    const int  q0    = qt * QBLK;
    const long xbase = ((long)b * T_LEN) * DIM + h * HD;

    // ---- Q fragments (gated, bf16), held in registers ----
    // A-frag layout: lane holds row (l&15), k = (l>>4)*8 + j (+32 per k-step)
    bf16x8 qa[2];
    {
        const int   qrow = q0 + w * 16 + lq;
        const float* qp  = x + xbase + (long)qrow * DIM + lh * 8;
        const float* gp  = bvq + h * HD + lh * 8;
        #pragma unroll
        for (int ks = 0; ks < 2; ++ks) {
            #pragma unroll
            for (int j = 0; j < 8; ++j) {
                qa[ks][j] = (__bf16)(qp[ks * 32 + j] * sgnf(gp[ks * 32 + j]));
            }
        }
    }

    f32x4 o[4];
    #pragma unroll
    for (int n = 0; n < 4; ++n) o[n] = (f32x4){0.f, 0.f, 0.f, 0.f};

    // staging decomposition: thread -> (row 0..63, 16-col quarter)
    const int r_st = tid >> 2;
    const int c0   = (tid & 3) * 16;
    const float* gk = bvk + h * HD + c0;
    const float* gv = bvv + h * HD + c0;

    for (int kvt = 0; kvt <= qt; ++kvt) {
        const int kv0 = kvt * KBLK;
        __syncthreads();   // previous tile's LDS reads done before overwrite

        // ---- stage K (row-major, sgn(bv_k)-gated) and V^T (sgn(bv_v)-gated) ----
        {
            const float* kp = x + xbase + (long)(kv0 + r_st) * DIM + c0;
            __bf16 kb[16];
            #pragma unroll
            for (int i = 0; i < 16; ++i)
                kb[i] = (__bf16)(kp[i] * sgnf(gk[i]));
            *(bf16x8*)&Kb[r_st][c0]     = *(bf16x8*)&kb[0];
            *(bf16x8*)&Kb[r_st][c0 + 8] = *(bf16x8*)&kb[8];
            #pragma unroll
            for (int i = 0; i < 16; ++i)
                Vt[c0 + i][r_st] = (__bf16)(kp[i] * sgnf(gv[i]));
        }
        __syncthreads();

        // ---- S = Q K^T : wave computes 16 q-rows x 64 k-cols ----
        f32x4 s[4];
        #pragma unroll
        for (int n = 0; n < 4; ++n) s[n] = (f32x4){0.f, 0.f, 0.f, 0.f};
        #pragma unroll
        for (int ks = 0; ks < 2; ++ks) {
            #pragma unroll
            for (int n = 0; n < 4; ++n) {
                bf16x8 kf = *(const bf16x8*)&Kb[n * 16 + lq][ks * 32 + lh * 8];
                s[n] = __builtin_amdgcn_mfma_f32_16x16x32_bf16(qa[ks], kf, s[n], 0, 0, 0);
            }
        }

        // ---- sigmoid (+ causal mask on diagonal tile) -> P (bf16, LDS) ----
        // C/D layout: col = l&15 (+16n), row = (l>>4)*4 + j
        const bool diag = (kvt == qt);
        #pragma unroll
        for (int n = 0; n < 4; ++n) {
            #pragma unroll
            for (int j = 0; j < 4; ++j) {
                float v = s[n][j];
                // sigmoid(0.5*v) = 1/(1 + 2^(-0.5*log2(e)*v))
                float p = __builtin_amdgcn_rcpf(
                              1.f + __builtin_amdgcn_exp2f(-0.72134752f * v));
                if (diag) {
                    int qg = w * 16 + lh * 4 + j;   // q local to block
                    int sg = n * 16 + lq;           // s local to tile (kv0==q0)
                    if (sg > qg) p = 0.f;
                }
                Pb[w][lh * 4 + j][n * 16 + lq] = (__bf16)p;
            }
        }
        // same-wave LDS RAW: DS ops are in-order per wave; compiler inserts waits

        // ---- O += P V  (B-frag from transposed V: contiguous b128) ----
        #pragma unroll
        for (int ks = 0; ks < 2; ++ks) {
            bf16x8 pf = *(const bf16x8*)&Pb[w][lq][ks * 32 + lh * 8];
            #pragma unroll
            for (int n = 0; n < 4; ++n) {
                bf16x8 vf = *(const bf16x8*)&Vt[n * 16 + lq][ks * 32 + lh * 8];
                o[n] = __builtin_amdgcn_mfma_f32_16x16x32_bf16(pf, vf, o[n], 0, 0, 0);
            }
        }
    }

    // ---- write O (fp32) ----
    float* op = out + ((long)b * T_LEN + q0 + w * 16) * DIM + h * HD;
    #pragma unroll
    for (int n = 0; n < 4; ++n) {
        #pragma unroll
        for (int j = 0; j < 4; ++j) {
            op[(long)(lh * 4 + j) * DIM + n * 16 + lq] = o[n][j];
        }
    }
}

extern "C" void kernel_launch(void* const* d_in, const int* in_sizes, int n_in,
                              void* d_out, int out_size, void* d_ws, size_t ws_size,
                              hipStream_t stream) {
    const float* x   = (const float*)d_in[0];
    const float* bvq = (const float*)d_in[1];
    const float* bvk = (const float*)d_in[2];
    const float* bvv = (const float*)d_in[3];
    float* out = (float*)d_out;

    const int grid = NB * NH * NQT;   // 1024 blocks
    mba_kernel<<<grid, 256, 0, stream>>>(x, bvq, bvk, bvv, out);
}

// Round 2
// 61.245 us; speedup vs baseline: 1.6262x; 1.6262x over previous
//
#include <hip/hip_runtime.h>
#include <hip/hip_bf16.h>
#include <stdint.h>

#define DIM 1024
#define T_LEN 2048
#define NB 2
#define NH 16
#define HD 64
#define NQT 32   // 2048/64 q-tiles

typedef float f32x4 __attribute__((ext_vector_type(4)));
typedef __bf16 bf16x8 __attribute__((ext_vector_type(8)));

__device__ __forceinline__ float sgnf(float v) {
    return (v > 0.f) ? 1.f : ((v < 0.f) ? -1.f : 0.f);
}

__device__ __forceinline__ float sigmoid_half(float v) {
    // sigmoid(0.5*v) = 1/(1 + 2^(-0.5*log2(e)*v))
    return __builtin_amdgcn_rcpf(1.f + __builtin_amdgcn_exp2f(-0.72134752f * v));
}

// async global -> LDS, 16B per lane; LDS dest is wave-uniform base + lane*16
__device__ __forceinline__ void gload16(const __bf16* g, __bf16* l) {
    __builtin_amdgcn_global_load_lds(
        (__attribute__((address_space(1))) void*)g,
        (__attribute__((address_space(3))) void*)l,
        16, 0, 0);
}

// ---------------- prepass: x(f32) -> Xb (bf16 row-major), Xt (bf16, [b][h][d][t]) ----------------
__global__ __launch_bounds__(256) void prep_kernel(
    const float* __restrict__ x, __bf16* __restrict__ xb, __bf16* __restrict__ xt)
{
    __shared__ __align__(16) __bf16 tile[64][72];   // 16B-aligned rows

    const int bid = blockIdx.x;
    const int h = bid & 15, tmp = bid >> 4, tt = tmp & 31, b = tmp >> 5;
    const int tid = threadIdx.x;
    const int r = tid >> 2, c0 = (tid & 3) * 16;

    const size_t rowbase = ((size_t)(b * T_LEN + tt * 64 + r)) * DIM + h * HD + c0;
    const float* xp = x + rowbase;

    __bf16 v[16];
    #pragma unroll
    for (int i = 0; i < 16; i += 4) {
        f32x4 f = *(const f32x4*)(xp + i);
        #pragma unroll
        for (int j = 0; j < 4; ++j) v[i + j] = (__bf16)f[j];
    }
    bf16x8 s0, s1;
    #pragma unroll
    for (int j = 0; j < 8; ++j) { s0[j] = v[j]; s1[j] = v[8 + j]; }
    *(bf16x8*)(xb + rowbase)     = s0;
    *(bf16x8*)(xb + rowbase + 8) = s1;
    *(bf16x8*)&tile[r][c0]     = s0;
    *(bf16x8*)&tile[r][c0 + 8] = s1;

    __syncthreads();

    const int d = tid >> 2, t0c = (tid & 3) * 16;
    __bf16 ov[16];
    #pragma unroll
    for (int i = 0; i < 16; ++i) ov[i] = tile[t0c + i][d];
    bf16x8 o0, o1;
    #pragma unroll
    for (int j = 0; j < 8; ++j) { o0[j] = ov[j]; o1[j] = ov[8 + j]; }
    const size_t obase = ((size_t)((b * NH + h) * HD + d)) * T_LEN + tt * 64 + t0c;
    *(bf16x8*)(xt + obase)     = o0;
    *(bf16x8*)(xt + obase + 8) = o1;
}

// ---------------- main kernel: paired q-tiles, dbuf K/V staging ----------------
__global__ __launch_bounds__(256, 2) void mba_main(
    const __bf16* __restrict__ xb, const __bf16* __restrict__ xt,
    const float* __restrict__ bvq, const float* __restrict__ bvk,
    const float* __restrict__ bvv, float* __restrict__ out)
{
    // K/V tiles: linear [64][64] bf16, swizzled CONTENT (src-side XOR), dbuf.
    __shared__ __align__(16) __bf16 Kb[2][64][64];
    __shared__ __align__(16) __bf16 Vb[2][64][64];
    // P scratch per wave per q-tile: [16 q][72] (16B-aligned rows)
    __shared__ __align__(16) __bf16 Pb[4][2][16][72];

    const int bid = blockIdx.x;
    const int p = bid & 15, bh = bid >> 4;
    const int b = bh >> 4, h = bh & 15;
    const int qtA = (NQT - 1) - p;   // heavy tile: stages 0..qtA
    const int qtB = p;               // light tile: dual while t <= qtB
    const int q0A = qtA * 64, q0B = qtB * 64;

    const int tid = threadIdx.x;
    const int w = tid >> 6, l = tid & 63, lq = l & 15, lh = l >> 4;

    const size_t xb_bh = (size_t)b * T_LEN * DIM + h * HD;      // row stride DIM
    const size_t xt_bh = (size_t)((b * NH + h) * HD) * T_LEN;   // row stride T_LEN

    // staging lane constants: lane covers (row = base + l>>3, slot = l&7),
    // source granule = slot ^ (row&7)  (involution; read applies same XOR)
    const int rr = l >> 3;
    const int sw = ((l & 7) ^ rr) << 3;   // element offset of swizzled 16B granule

    auto STAGE = [&](int buf, int kvt) {
        const int kv0 = kvt * 64;
        #pragma unroll
        for (int pt = 0; pt < 2; ++pt) {
            const int r0 = w * 8 + pt * 32;
            gload16(xb + xb_bh + (size_t)(kv0 + r0 + rr) * DIM + sw, &Kb[buf][r0][0]);
            gload16(xt + xt_bh + (size_t)(r0 + rr) * T_LEN + kv0 + sw, &Vb[buf][r0][0]);
        }
    };

    STAGE(0, 0);   // prefetch tile 0 while we set up Q

    // ---- Q fragments, with folded sign(bvq)*sign(bvk) (exact: ±1/0) ----
    bf16x8 qA[2], qB[2];
    {
        const float* bq = bvq + h * HD;
        const float* bk = bvk + h * HD;
        #pragma unroll
        for (int ks = 0; ks < 2; ++ks) {
            const int d0 = ks * 32 + lh * 8;
            bf16x8 va = *(const bf16x8*)(xb + xb_bh + (size_t)(q0A + w * 16 + lq) * DIM + d0);
            bf16x8 vb = *(const bf16x8*)(xb + xb_bh + (size_t)(q0B + w * 16 + lq) * DIM + d0);
            #pragma unroll
            for (int j = 0; j < 8; ++j) {
                float f = sgnf(bq[d0 + j]) * sgnf(bk[d0 + j]);
                qA[ks][j] = (__bf16)((float)va[j] * f);
                qB[ks][j] = (__bf16)((float)vb[j] * f);
            }
        }
    }
    // V-sign for epilogue (column d = 16n+lq)
    float sv[4];
    #pragma unroll
    for (int n = 0; n < 4; ++n) sv[n] = sgnf(bvv[h * HD + n * 16 + lq]);

    f32x4 oA[4], oB[4];
    #pragma unroll
    for (int n = 0; n < 4; ++n) { oA[n] = (f32x4){0,0,0,0}; oB[n] = (f32x4){0,0,0,0}; }

    __syncthreads();   // drains vmcnt -> tile 0 staged
    int cur = 0;

    auto body = [&](bool dual, int t) {
        if (t < qtA) STAGE(cur ^ 1, t + 1);

        // ---- S = Q K^T ----
        f32x4 sA[4], sB[4];
        #pragma unroll
        for (int n = 0; n < 4; ++n) { sA[n] = (f32x4){0,0,0,0}; sB[n] = (f32x4){0,0,0,0}; }
        #pragma unroll
        for (int ks = 0; ks < 2; ++ks) {
            #pragma unroll
            for (int n = 0; n < 4; ++n) {
                const int r = n * 16 + lq;
                bf16x8 kf = *(const bf16x8*)((const char*)&Kb[cur][r][0]
                              + ((ks * 64 + lh * 16) ^ ((r & 7) << 4)));
                sA[n] = __builtin_amdgcn_mfma_f32_16x16x32_bf16(qA[ks], kf, sA[n], 0, 0, 0);
                if (dual)
                    sB[n] = __builtin_amdgcn_mfma_f32_16x16x32_bf16(qB[ks], kf, sB[n], 0, 0, 0);
            }
        }

        // ---- sigmoid + causal mask -> P (bf16, LDS) ----
        const bool dA = (t == qtA), dB = (t == qtB);
        #pragma unroll
        for (int n = 0; n < 4; ++n) {
            #pragma unroll
            for (int j = 0; j < 4; ++j) {
                const int qg = w * 16 + lh * 4 + j;   // q local to block
                const int sg = n * 16 + lq;           // s local to tile
                {
                    float pp = sigmoid_half(sA[n][j]);
                    if (dA && sg > qg) pp = 0.f;
                    Pb[w][0][lh * 4 + j][n * 16 + lq] = (__bf16)pp;
                }
                if (dual) {
                    float pp = sigmoid_half(sB[n][j]);
                    if (dB && sg > qg) pp = 0.f;
                    Pb[w][1][lh * 4 + j][n * 16 + lq] = (__bf16)pp;
                }
            }
        }

        // ---- P fragments (same-wave LDS RAW: in-order DS) ----
        bf16x8 pA[2], pB[2];
        #pragma unroll
        for (int ks = 0; ks < 2; ++ks) {
            pA[ks] = *(const bf16x8*)&Pb[w][0][lq][ks * 32 + lh * 8];
            if (dual) pB[ks] = *(const bf16x8*)&Pb[w][1][lq][ks * 32 + lh * 8];
        }

        // ---- O += P V ----
        #pragma unroll
        for (int ks = 0; ks < 2; ++ks) {
            #pragma unroll
            for (int n = 0; n < 4; ++n) {
                const int r = n * 16 + lq;
                bf16x8 vf = *(const bf16x8*)((const char*)&Vb[cur][r][0]
                              + ((ks * 64 + lh * 16) ^ ((r & 7) << 4)));
                oA[n] = __builtin_amdgcn_mfma_f32_16x16x32_bf16(pA[ks], vf, oA[n], 0, 0, 0);
                if (dual)
                    oB[n] = __builtin_amdgcn_mfma_f32_16x16x32_bf16(pB[ks], vf, oB[n], 0, 0, 0);
            }
        }
        __syncthreads();   // drains staged loads for t+1; protects dbuf reuse
        cur ^= 1;
    };

    int t = 0;
    for (; t <= qtB; ++t) body(true, t);    // shared range: both q-tiles per staged tile
    for (; t <= qtA; ++t) body(false, t);   // heavy tile alone

    // ---- epilogue: apply sign(bvv) and store ----
    float* opA = out + ((size_t)(b * T_LEN + q0A + w * 16)) * DIM + h * HD;
    float* opB = out + ((size_t)(b * T_LEN + q0B + w * 16)) * DIM + h * HD;
    #pragma unroll
    for (int n = 0; n < 4; ++n) {
        #pragma unroll
        for (int j = 0; j < 4; ++j) {
            opA[(size_t)(lh * 4 + j) * DIM + n * 16 + lq] = oA[n][j] * sv[n];
            opB[(size_t)(lh * 4 + j) * DIM + n * 16 + lq] = oB[n][j] * sv[n];
        }
    }
}

// ---------------- fallback (round-1 kernel) if ws too small ----------------
__global__ __launch_bounds__(256) void mba_fallback(
    const float* __restrict__ x,
    const float* __restrict__ bvq,
    const float* __restrict__ bvk,
    const float* __restrict__ bvv,
    float* __restrict__ out)
{
    __shared__ __align__(16) __bf16 Kb[64][72];
    __shared__ __align__(16) __bf16 Vt[HD][72];
    __shared__ __align__(16) __bf16 Pb[4][16][72];

    const int bid = blockIdx.x;
    const int qt  = (NQT - 1) - (bid & (NQT - 1));
    const int bh  = bid >> 5;
    const int b   = bh >> 4;
    const int h   = bh & 15;

    const int tid = threadIdx.x;
    const int w   = tid >> 6;
    const int l   = tid & 63;
    const int lq  = l & 15;
    const int lh  = l >> 4;

    const int  q0    = qt * 64;
    const long xbase = ((long)b * T_LEN) * DIM + h * HD;

    bf16x8 qa[2];
    {
        const int   qrow = q0 + w * 16 + lq;
        const float* qp  = x + xbase + (long)qrow * DIM + lh * 8;
        const float* gp  = bvq + h * HD + lh * 8;
        #pragma unroll
        for (int ks = 0; ks < 2; ++ks)
            #pragma unroll
            for (int j = 0; j < 8; ++j)
                qa[ks][j] = (__bf16)(qp[ks * 32 + j] * sgnf(gp[ks * 32 + j]));
    }

    f32x4 o[4];
    #pragma unroll
    for (int n = 0; n < 4; ++n) o[n] = (f32x4){0.f, 0.f, 0.f, 0.f};

    const int r_st = tid >> 2;
    const int c0   = (tid & 3) * 16;
    const float* gk = bvk + h * HD + c0;
    const float* gv = bvv + h * HD + c0;

    for (int kvt = 0; kvt <= qt; ++kvt) {
        const int kv0 = kvt * 64;
        __syncthreads();
        {
            const float* kp = x + xbase + (long)(kv0 + r_st) * DIM + c0;
            __bf16 kb[16];
            #pragma unroll
            for (int i = 0; i < 16; ++i) kb[i] = (__bf16)(kp[i] * sgnf(gk[i]));
            *(bf16x8*)&Kb[r_st][c0]     = *(bf16x8*)&kb[0];
            *(bf16x8*)&Kb[r_st][c0 + 8] = *(bf16x8*)&kb[8];
            #pragma unroll
            for (int i = 0; i < 16; ++i)
                Vt[c0 + i][r_st] = (__bf16)(kp[i] * sgnf(gv[i]));
        }
        __syncthreads();

        f32x4 s[4];
        #pragma unroll
        for (int n = 0; n < 4; ++n) s[n] = (f32x4){0.f, 0.f, 0.f, 0.f};
        #pragma unroll
        for (int ks = 0; ks < 2; ++ks)
            #pragma unroll
            for (int n = 0; n < 4; ++n) {
                bf16x8 kf = *(const bf16x8*)&Kb[n * 16 + lq][ks * 32 + lh * 8];
                s[n] = __builtin_amdgcn_mfma_f32_16x16x32_bf16(qa[ks], kf, s[n], 0, 0, 0);
            }

        const bool diag = (kvt == qt);
        #pragma unroll
        for (int n = 0; n < 4; ++n)
            #pragma unroll
            for (int j = 0; j < 4; ++j) {
                float p = sigmoid_half(s[n][j]);
                if (diag && (n * 16 + lq) > (w * 16 + lh * 4 + j)) p = 0.f;
                Pb[w][lh * 4 + j][n * 16 + lq] = (__bf16)p;
            }

        #pragma unroll
        for (int ks = 0; ks < 2; ++ks) {
            bf16x8 pf = *(const bf16x8*)&Pb[w][lq][ks * 32 + lh * 8];
            #pragma unroll
            for (int n = 0; n < 4; ++n) {
                bf16x8 vf = *(const bf16x8*)&Vt[n * 16 + lq][ks * 32 + lh * 8];
                o[n] = __builtin_amdgcn_mfma_f32_16x16x32_bf16(pf, vf, o[n], 0, 0, 0);
            }
        }
    }

    float* op = out + ((long)b * T_LEN + q0 + w * 16) * DIM + h * HD;
    #pragma unroll
    for (int n = 0; n < 4; ++n)
        #pragma unroll
        for (int j = 0; j < 4; ++j)
            op[(long)(lh * 4 + j) * DIM + n * 16 + lq] = o[n][j] * 1.f;
}

extern "C" void kernel_launch(void* const* d_in, const int* in_sizes, int n_in,
                              void* d_out, int out_size, void* d_ws, size_t ws_size,
                              hipStream_t stream) {
    (void)in_sizes; (void)n_in; (void)out_size;
    const float* x   = (const float*)d_in[0];
    const float* bvq = (const float*)d_in[1];
    const float* bvk = (const float*)d_in[2];
    const float* bvv = (const float*)d_in[3];
    float* out = (float*)d_out;

    const size_t XB_BYTES = (size_t)NB * T_LEN * DIM * sizeof(__bf16);  // 8 MB
    const size_t XT_BYTES = XB_BYTES;                                    // 8 MB

    if (ws_size < XB_BYTES + XT_BYTES) {
        mba_fallback<<<NB * NH * NQT, 256, 0, stream>>>(x, bvq, bvk, bvv, out);
        return;
    }

    __bf16* xb = (__bf16*)d_ws;
    __bf16* xt = xb + (size_t)NB * T_LEN * DIM;

    prep_kernel<<<NB * NQT * NH, 256, 0, stream>>>(x, xb, xt);
    mba_main<<<NB * NH * (NQT / 2), 256, 0, stream>>>(xb, xt, bvq, bvk, bvv, out);
}

// Round 3
// 55.322 us; speedup vs baseline: 1.8003x; 1.1071x over previous
//
#include <hip/hip_runtime.h>
#include <hip/hip_bf16.h>
#include <stdint.h>

#define DIM 1024
#define T_LEN 2048
#define NB 2
#define NH 16
#define HD 64
#define NQT 32   // 2048/64 q-tiles

typedef float f32x4 __attribute__((ext_vector_type(4)));
typedef __bf16 bf16x8 __attribute__((ext_vector_type(8)));
typedef __bf16 bf16x2 __attribute__((ext_vector_type(2)));

__device__ __forceinline__ float sgnf(float v) {
    return (v > 0.f) ? 1.f : ((v < 0.f) ? -1.f : 0.f);
}

__device__ __forceinline__ float sigmoid_half(float v) {
    // sigmoid(0.5*v) = 1/(1 + 2^(-0.5*log2(e)*v))
    return __builtin_amdgcn_rcpf(1.f + __builtin_amdgcn_exp2f(-0.72134752f * v));
}

// async global -> LDS, 16B per lane; LDS dest is wave-uniform base + lane*16
__device__ __forceinline__ void gload16(const __bf16* g, __bf16* l) {
    __builtin_amdgcn_global_load_lds(
        (__attribute__((address_space(1))) void*)g,
        (__attribute__((address_space(3))) void*)l,
        16, 0, 0);
}

// ---------------- prepass: x(f32) -> Xb (bf16 row-major), Xt (bf16, [b][h][d][t]) ----------------
__global__ __launch_bounds__(256) void prep_kernel(
    const float* __restrict__ x, __bf16* __restrict__ xb, __bf16* __restrict__ xt)
{
    __shared__ __align__(16) __bf16 tile[64][72];

    const int bid = blockIdx.x;
    const int h = bid & 15, tmp = bid >> 4, tt = tmp & 31, b = tmp >> 5;
    const int tid = threadIdx.x;
    const int r = tid >> 2, c0 = (tid & 3) * 16;

    const size_t rowbase = ((size_t)(b * T_LEN + tt * 64 + r)) * DIM + h * HD + c0;
    const float* xp = x + rowbase;

    __bf16 v[16];
    #pragma unroll
    for (int i = 0; i < 16; i += 4) {
        f32x4 f = *(const f32x4*)(xp + i);
        #pragma unroll
        for (int j = 0; j < 4; ++j) v[i + j] = (__bf16)f[j];
    }
    bf16x8 s0, s1;
    #pragma unroll
    for (int j = 0; j < 8; ++j) { s0[j] = v[j]; s1[j] = v[8 + j]; }
    *(bf16x8*)(xb + rowbase)     = s0;
    *(bf16x8*)(xb + rowbase + 8) = s1;
    *(bf16x8*)&tile[r][c0]     = s0;
    *(bf16x8*)&tile[r][c0 + 8] = s1;

    __syncthreads();

    const int d = tid >> 2, t0c = (tid & 3) * 16;
    __bf16 ov[16];
    #pragma unroll
    for (int i = 0; i < 16; ++i) ov[i] = tile[t0c + i][d];
    bf16x8 o0, o1;
    #pragma unroll
    for (int j = 0; j < 8; ++j) { o0[j] = ov[j]; o1[j] = ov[8 + j]; }
    const size_t obase = ((size_t)((b * NH + h) * HD + d)) * T_LEN + tt * 64 + t0c;
    *(bf16x8*)(xt + obase)     = o0;
    *(bf16x8*)(xt + obase + 8) = o1;
}

// ---------------- main kernel: paired q-tiles, 3-buf ring, counted vmcnt ----------------
__global__ __launch_bounds__(256, 2) void mba_main(
    const __bf16* __restrict__ xb, const __bf16* __restrict__ xt,
    const float* __restrict__ bvq, const float* __restrict__ bvk,
    const float* __restrict__ bvv, float* __restrict__ out)
{
    // 3-deep ring of K/V tiles: linear [64][64] bf16, swizzled CONTENT.
    __shared__ __align__(16) __bf16 Kb[3][64][64];
    __shared__ __align__(16) __bf16 Vb[3][64][64];
    // P scratch per wave per q-tile: row = q (16), col = s (64, +pad)
    __shared__ __align__(16) __bf16 Pt[4][2][16][72];

    const int bid = blockIdx.x;
    const int p = bid & 15, bh = bid >> 4;
    const int b = bh >> 4, h = bh & 15;
    const int qtA = (NQT - 1) - p;   // heavy tile: stages 0..qtA (>=16)
    const int qtB = p;               // light tile: dual while t <= qtB (<=15)
    const int q0A = qtA * 64, q0B = qtB * 64;

    const int tid = threadIdx.x;
    const int w = tid >> 6, l = tid & 63, lq = l & 15, lh = l >> 4;

    const size_t xb_bh = (size_t)b * T_LEN * DIM + h * HD;      // row stride DIM
    const size_t xt_bh = (size_t)((b * NH + h) * HD) * T_LEN;   // row stride T_LEN

    // staging: lane covers (row = base + l>>3, granule = l&7), source granule
    // pre-swizzled by row (involution; reads apply the same XOR)
    const int rr = l >> 3;
    const int sw = ((l & 7) ^ rr) << 3;

    auto STAGE = [&](int buf, int kvt) {
        const int kv0 = kvt * 64;
        #pragma unroll
        for (int pt = 0; pt < 2; ++pt) {
            const int r0 = w * 8 + pt * 32;
            gload16(xb + xb_bh + (size_t)(kv0 + r0 + rr) * DIM + sw, &Kb[buf][r0][0]);
            gload16(xt + xt_bh + (size_t)(r0 + rr) * T_LEN + kv0 + sw, &Vb[buf][r0][0]);
        }
    };

    STAGE(0, 0);
    STAGE(1, 1);   // qtA >= 16, both tiles always exist

    // ---- Q fragments with folded sign(bvq)*sign(bvk); used as the MFMA B-operand ----
    bf16x8 qA[2], qB[2];
    {
        const float* bq = bvq + h * HD;
        const float* bk = bvk + h * HD;
        #pragma unroll
        for (int ks = 0; ks < 2; ++ks) {
            const int d0 = ks * 32 + lh * 8;
            bf16x8 va = *(const bf16x8*)(xb + xb_bh + (size_t)(q0A + w * 16 + lq) * DIM + d0);
            bf16x8 vb = *(const bf16x8*)(xb + xb_bh + (size_t)(q0B + w * 16 + lq) * DIM + d0);
            #pragma unroll
            for (int j = 0; j < 8; ++j) {
                float f = sgnf(bq[d0 + j]) * sgnf(bk[d0 + j]);
                qA[ks][j] = (__bf16)((float)va[j] * f);
                qB[ks][j] = (__bf16)((float)vb[j] * f);
            }
        }
    }
    float sv[4];
    #pragma unroll
    for (int n = 0; n < 4; ++n) sv[n] = sgnf(bvv[h * HD + n * 16 + lq]);

    f32x4 oA[4], oB[4];
    #pragma unroll
    for (int n = 0; n < 4; ++n) { oA[n] = (f32x4){0,0,0,0}; oB[n] = (f32x4){0,0,0,0}; }

    int cur = 0;

    // body: counted-vmcnt pipeline. Per wave: 4 gload16 in flight per staged
    // tile; steady state has tiles {t, t+1} outstanding -> vmcnt(4) retires
    // exactly tile t. Last body has only tile t outstanding -> vmcnt(0).
    auto body = [&](bool dual, int t, bool last) {
        if (last) { asm volatile("s_waitcnt vmcnt(0)" ::: "memory"); }
        else      { asm volatile("s_waitcnt vmcnt(4)" ::: "memory"); }
        __builtin_amdgcn_sched_barrier(0);
        __builtin_amdgcn_s_barrier();      // all waves' tile-t loads complete
        __builtin_amdgcn_sched_barrier(0);
        asm volatile("" ::: "memory");

        if (t + 2 <= qtA) {                // recycled buf was read in body(t-1)
            int stg = cur + 2; if (stg >= 3) stg -= 3;
            STAGE(stg, t + 2);
        }

        // ---- S^T = K Q^T : lane (lq,lh) holds S[s = n*16+lh*4+j][q = w*16+lq]
        f32x4 sA[4], sB[4];
        #pragma unroll
        for (int n = 0; n < 4; ++n) { sA[n] = (f32x4){0,0,0,0}; sB[n] = (f32x4){0,0,0,0}; }
        #pragma unroll
        for (int ks = 0; ks < 2; ++ks) {
            #pragma unroll
            for (int n = 0; n < 4; ++n) {
                const int r = n * 16 + lq;
                bf16x8 kf = *(const bf16x8*)((const char*)&Kb[cur][r][0]
                              + ((ks * 64 + lh * 16) ^ ((r & 7) << 4)));
                sA[n] = __builtin_amdgcn_mfma_f32_16x16x32_bf16(kf, qA[ks], sA[n], 0, 0, 0);
                if (dual)
                    sB[n] = __builtin_amdgcn_mfma_f32_16x16x32_bf16(kf, qB[ks], sB[n], 0, 0, 0);
            }
        }

        // ---- sigmoid + causal mask -> packed b32 P writes (s-pairs lane-local)
        // dual bodies: only tile B can be diagonal (qtB < 16 <= qtA);
        // single bodies: only tile A exists.
        const int q_loc = w * 16 + lq;
        #pragma unroll
        for (int n = 0; n < 4; ++n) {
            #pragma unroll
            for (int hh = 0; hh < 2; ++hh) {
                const int s0 = n * 16 + lh * 4 + 2 * hh;
                {
                    float p0 = sigmoid_half(sA[n][2 * hh]);
                    float p1 = sigmoid_half(sA[n][2 * hh + 1]);
                    if (!dual && t == qtA) {
                        if (s0 > q_loc)     p0 = 0.f;
                        if (s0 + 1 > q_loc) p1 = 0.f;
                    }
                    *(bf16x2*)&Pt[w][0][lq][s0] = (bf16x2){(__bf16)p0, (__bf16)p1};
                }
                if (dual) {
                    float p0 = sigmoid_half(sB[n][2 * hh]);
                    float p1 = sigmoid_half(sB[n][2 * hh + 1]);
                    if (t == qtB) {
                        if (s0 > q_loc)     p0 = 0.f;
                        if (s0 + 1 > q_loc) p1 = 0.f;
                    }
                    *(bf16x2*)&Pt[w][1][lq][s0] = (bf16x2){(__bf16)p0, (__bf16)p1};
                }
            }
        }

        // ---- P fragments (same-wave LDS RAW; contiguous b128) ----
        bf16x8 pA[2], pB[2];
        #pragma unroll
        for (int ks = 0; ks < 2; ++ks) {
            pA[ks] = *(const bf16x8*)&Pt[w][0][lq][ks * 32 + lh * 8];
            if (dual) pB[ks] = *(const bf16x8*)&Pt[w][1][lq][ks * 32 + lh * 8];
        }

        // ---- O += P V ----
        #pragma unroll
        for (int ks = 0; ks < 2; ++ks) {
            #pragma unroll
            for (int n = 0; n < 4; ++n) {
                const int r = n * 16 + lq;
                bf16x8 vf = *(const bf16x8*)((const char*)&Vb[cur][r][0]
                              + ((ks * 64 + lh * 16) ^ ((r & 7) << 4)));
                oA[n] = __builtin_amdgcn_mfma_f32_16x16x32_bf16(pA[ks], vf, oA[n], 0, 0, 0);
                if (dual)
                    oB[n] = __builtin_amdgcn_mfma_f32_16x16x32_bf16(pB[ks], vf, oB[n], 0, 0, 0);
            }
        }
        cur = (cur == 2) ? 0 : cur + 1;
    };

    int t = 0;
    for (; t <= qtB; ++t) body(true, t, false);   // qtB <= 15 < qtA: never last
    for (; t < qtA; ++t)  body(false, t, false);
    body(false, qtA, true);

    // ---- epilogue: apply sign(bvv) and store ----
    float* opA = out + ((size_t)(b * T_LEN + q0A + w * 16)) * DIM + h * HD;
    float* opB = out + ((size_t)(b * T_LEN + q0B + w * 16)) * DIM + h * HD;
    #pragma unroll
    for (int n = 0; n < 4; ++n) {
        #pragma unroll
        for (int j = 0; j < 4; ++j) {
            opA[(size_t)(lh * 4 + j) * DIM + n * 16 + lq] = oA[n][j] * sv[n];
            opB[(size_t)(lh * 4 + j) * DIM + n * 16 + lq] = oB[n][j] * sv[n];
        }
    }
}

// ---------------- fallback (round-1 kernel) if ws too small ----------------
__global__ __launch_bounds__(256) void mba_fallback(
    const float* __restrict__ x,
    const float* __restrict__ bvq,
    const float* __restrict__ bvk,
    const float* __restrict__ bvv,
    float* __restrict__ out)
{
    __shared__ __align__(16) __bf16 Kb[64][72];
    __shared__ __align__(16) __bf16 Vt[HD][72];
    __shared__ __align__(16) __bf16 Pb[4][16][72];

    const int bid = blockIdx.x;
    const int qt  = (NQT - 1) - (bid & (NQT - 1));
    const int bh  = bid >> 5;
    const int b   = bh >> 4;
    const int h   = bh & 15;

    const int tid = threadIdx.x;
    const int w   = tid >> 6;
    const int l   = tid & 63;
    const int lq  = l & 15;
    const int lh  = l >> 4;

    const int  q0    = qt * 64;
    const long xbase = ((long)b * T_LEN) * DIM + h * HD;

    bf16x8 qa[2];
    {
        const int   qrow = q0 + w * 16 + lq;
        const float* qp  = x + xbase + (long)qrow * DIM + lh * 8;
        const float* gp  = bvq + h * HD + lh * 8;
        #pragma unroll
        for (int ks = 0; ks < 2; ++ks)
            #pragma unroll
            for (int j = 0; j < 8; ++j)
                qa[ks][j] = (__bf16)(qp[ks * 32 + j] * sgnf(gp[ks * 32 + j]));
    }

    f32x4 o[4];
    #pragma unroll
    for (int n = 0; n < 4; ++n) o[n] = (f32x4){0.f, 0.f, 0.f, 0.f};

    const int r_st = tid >> 2;
    const int c0   = (tid & 3) * 16;
    const float* gk = bvk + h * HD + c0;
    const float* gv = bvv + h * HD + c0;

    for (int kvt = 0; kvt <= qt; ++kvt) {
        const int kv0 = kvt * 64;
        __syncthreads();
        {
            const float* kp = x + xbase + (long)(kv0 + r_st) * DIM + c0;
            __bf16 kb[16];
            #pragma unroll
            for (int i = 0; i < 16; ++i) kb[i] = (__bf16)(kp[i] * sgnf(gk[i]));
            *(bf16x8*)&Kb[r_st][c0]     = *(bf16x8*)&kb[0];
            *(bf16x8*)&Kb[r_st][c0 + 8] = *(bf16x8*)&kb[8];
            #pragma unroll
            for (int i = 0; i < 16; ++i)
                Vt[c0 + i][r_st] = (__bf16)(kp[i] * sgnf(gv[i]));
        }
        __syncthreads();

        f32x4 s[4];
        #pragma unroll
        for (int n = 0; n < 4; ++n) s[n] = (f32x4){0.f, 0.f, 0.f, 0.f};
        #pragma unroll
        for (int ks = 0; ks < 2; ++ks)
            #pragma unroll
            for (int n = 0; n < 4; ++n) {
                bf16x8 kf = *(const bf16x8*)&Kb[n * 16 + lq][ks * 32 + lh * 8];
                s[n] = __builtin_amdgcn_mfma_f32_16x16x32_bf16(qa[ks], kf, s[n], 0, 0, 0);
            }

        const bool diag = (kvt == qt);
        #pragma unroll
        for (int n = 0; n < 4; ++n)
            #pragma unroll
            for (int j = 0; j < 4; ++j) {
                float p = sigmoid_half(s[n][j]);
                if (diag && (n * 16 + lq) > (w * 16 + lh * 4 + j)) p = 0.f;
                Pb[w][lh * 4 + j][n * 16 + lq] = (__bf16)p;
            }

        #pragma unroll
        for (int ks = 0; ks < 2; ++ks) {
            bf16x8 pf = *(const bf16x8*)&Pb[w][lq][ks * 32 + lh * 8];
            #pragma unroll
            for (int n = 0; n < 4; ++n) {
                bf16x8 vf = *(const bf16x8*)&Vt[n * 16 + lq][ks * 32 + lh * 8];
                o[n] = __builtin_amdgcn_mfma_f32_16x16x32_bf16(pf, vf, o[n], 0, 0, 0);
            }
        }
    }

    float* op = out + ((long)b * T_LEN + q0 + w * 16) * DIM + h * HD;
    #pragma unroll
    for (int n = 0; n < 4; ++n)
        #pragma unroll
        for (int j = 0; j < 4; ++j)
            op[(long)(lh * 4 + j) * DIM + n * 16 + lq] = o[n][j];
}

extern "C" void kernel_launch(void* const* d_in, const int* in_sizes, int n_in,
                              void* d_out, int out_size, void* d_ws, size_t ws_size,
                              hipStream_t stream) {
    (void)in_sizes; (void)n_in; (void)out_size;
    const float* x   = (const float*)d_in[0];
    const float* bvq = (const float*)d_in[1];
    const float* bvk = (const float*)d_in[2];
    const float* bvv = (const float*)d_in[3];
    float* out = (float*)d_out;

    const size_t XB_BYTES = (size_t)NB * T_LEN * DIM * sizeof(__bf16);  // 8 MB
    const size_t XT_BYTES = XB_BYTES;                                    // 8 MB

    if (ws_size < XB_BYTES + XT_BYTES) {
        mba_fallback<<<NB * NH * NQT, 256, 0, stream>>>(x, bvq, bvk, bvv, out);
        return;
    }

    __bf16* xb = (__bf16*)d_ws;
    __bf16* xt = xb + (size_t)NB * T_LEN * DIM;

    prep_kernel<<<NB * NQT * NH, 256, 0, stream>>>(x, xb, xt);
    mba_main<<<NB * NH * (NQT / 2), 256, 0, stream>>>(xb, xt, bvq, bvk, bvv, out);
}